// Round 1
// baseline (1394.258 us; speedup 1.0000x reference)
//
#include <hip/hip_runtime.h>

constexpr int kB = 8, kC = 256, kNh = 8, kDK = 64, kDV = 64;
constexpr int kHW = 1024;           // H*W = 32*32
constexpr int kO  = kNh * kDK;      // 512

// ---------------------------------------------------------------------------
// conv1x1 as batched GEMM: out[b][o][hw] = (sum_c Wm[o][c]*x[b][c][hw] + bias[o]) * scale
// 64x64 output tile per block, K-steps of 16, 256 threads, 4x4 micro-tile.
// ---------------------------------------------------------------------------
__global__ __launch_bounds__(256) void conv1x1_k(
    const float* __restrict__ x, const float* __restrict__ Wm,
    const float* __restrict__ bias, float* __restrict__ out,
    int Cdim, int Odim, float scale)
{
  __shared__ float sW[16][68];   // [k][m], padded
  __shared__ float sX[16][64];   // [k][n]
  const int b  = blockIdx.z;
  const int o0 = blockIdx.y * 64;
  const int n0 = blockIdx.x * 64;
  const float* xb = x + (size_t)b * Cdim * kHW;
  float* ob = out + (size_t)b * Odim * kHW;
  const int tid = threadIdx.x;
  const int tx = tid & 15, ty = tid >> 4;
  const int lm = tid >> 2, lk = (tid & 3) * 4;   // W-tile loader coords
  const int xk = tid >> 4, xn = (tid & 15) * 4;  // X-tile loader coords

  float acc[4][4] = {};
  for (int k0 = 0; k0 < Cdim; k0 += 16) {
    const float4 wv = *reinterpret_cast<const float4*>(&Wm[(size_t)(o0 + lm) * Cdim + k0 + lk]);
    const float4 xv = *reinterpret_cast<const float4*>(&xb[(size_t)(k0 + xk) * kHW + n0 + xn]);
    __syncthreads();
    sW[lk + 0][lm] = wv.x;
    sW[lk + 1][lm] = wv.y;
    sW[lk + 2][lm] = wv.z;
    sW[lk + 3][lm] = wv.w;
    *reinterpret_cast<float4*>(&sX[xk][xn]) = xv;
    __syncthreads();
#pragma unroll
    for (int kk = 0; kk < 16; ++kk) {
      const float4 a4 = *reinterpret_cast<const float4*>(&sW[kk][ty * 4]);
      const float4 b4 = *reinterpret_cast<const float4*>(&sX[kk][tx * 4]);
      const float am[4] = {a4.x, a4.y, a4.z, a4.w};
      const float bv[4] = {b4.x, b4.y, b4.z, b4.w};
#pragma unroll
      for (int mi = 0; mi < 4; ++mi)
#pragma unroll
        for (int ni = 0; ni < 4; ++ni)
          acc[mi][ni] += am[mi] * bv[ni];
    }
  }
#pragma unroll
  for (int mi = 0; mi < 4; ++mi) {
    const int o = o0 + ty * 4 + mi;
    const float bb = bias[o];
    float4 r;
    r.x = (acc[mi][0] + bb) * scale;
    r.y = (acc[mi][1] + bb) * scale;
    r.z = (acc[mi][2] + bb) * scale;
    r.w = (acc[mi][3] + bb) * scale;
    *reinterpret_cast<float4*>(&ob[(size_t)o * kHW + n0 + tx * 4]) = r;
  }
}

// ---------------------------------------------------------------------------
// Attention: one block = (b*8+nh, 16 query rows). q/k/v layout [bn][d][hw].
// S[16][1024] staged in LDS; rows are wave-private (wave w owns rows 4w..4w+3).
// rel logits: logits[i=(x,y)][j=(x',y')] += Rw[i][y'-y+31] + Rh[i][x'-x+31].
// Output written at bn*65536 + i*64 + d, which IS the reference's
// reshape-combined [B][512][1024] layout (reshape, not transpose!).
// ---------------------------------------------------------------------------
__global__ __launch_bounds__(256) void attn_k(
    const float* __restrict__ qb, const float* __restrict__ kb,
    const float* __restrict__ vb, const float* __restrict__ relw,
    const float* __restrict__ relh, float* __restrict__ attn)
{
  __shared__ float qt[64 * 16];     // [d][i]  (q already *DK^-0.5)
  __shared__ float rw[16 * 64];     // [i][m], m<63
  __shared__ float rh[16 * 64];
  __shared__ float S [16 * 1024];   // [i][j]
  __shared__ float vT[64 * 65];     // [j][d] chunk, padded (+1 -> conflict-free)

  const int bn = blockIdx.y;
  const int i0 = blockIdx.x * 16;
  const float* q_ = qb + (size_t)bn * 64 * kHW;
  const float* k_ = kb + (size_t)bn * 64 * kHW;
  const float* v_ = vb + (size_t)bn * 64 * kHW;
  const int tid = threadIdx.x;
  const int ig = tid >> 6, lane = tid & 63;   // wave id, lane

  // q tile -> LDS transposed [d][i]
  for (int e = tid; e < 1024; e += 256) {
    const int d = e >> 4, i = e & 15;
    qt[d * 16 + i] = q_[d * kHW + i0 + i];
  }
  __syncthreads();

  // relative logits rows: rw[i][m] = q_i . relw[m], rh[i][m] = q_i . relh[m]
  for (int e = tid; e < 2 * 16 * 63; e += 256) {
    const int sel = (e >= 16 * 63) ? 1 : 0;
    const int r = sel ? e - 16 * 63 : e;
    const int i = r / 63, m = r - i * 63;
    const float* rk = (sel ? relh : relw) + m * 64;
    float a = 0.f;
#pragma unroll
    for (int d = 0; d < 64; ++d) a += qt[d * 16 + i] * rk[d];
    (sel ? rh : rw)[i * 64 + m] = a;
  }
  __syncthreads();

  // S = q^T k, rows ig*4..+3, 4x4 micro-tiles over j
  for (int pass = 0; pass < 4; ++pass) {
    const int j0 = pass * 256 + lane * 4;
    float sa[4][4] = {};
    for (int d = 0; d < 64; ++d) {
      const float4 kv = *reinterpret_cast<const float4*>(&k_[d * kHW + j0]);
      const float4 qv = *reinterpret_cast<const float4*>(&qt[d * 16 + ig * 4]);
      const float qm[4] = {qv.x, qv.y, qv.z, qv.w};
#pragma unroll
      for (int mi = 0; mi < 4; ++mi) {
        sa[mi][0] += qm[mi] * kv.x;
        sa[mi][1] += qm[mi] * kv.y;
        sa[mi][2] += qm[mi] * kv.z;
        sa[mi][3] += qm[mi] * kv.w;
      }
    }
#pragma unroll
    for (int mi = 0; mi < 4; ++mi) {
      const float4 r = {sa[mi][0], sa[mi][1], sa[mi][2], sa[mi][3]};
      *reinterpret_cast<float4*>(&S[(ig * 4 + mi) * kHW + j0]) = r;
    }
  }
  // no barrier needed: each wave's softmax reads only rows it just wrote

  const int xq = i0 >> 5;           // query row (constant within 16-tile)
  float rsum[4];
#pragma unroll
  for (int mi = 0; mi < 4; ++mi) {
    const int r = ig * 4 + mi;
    const int yq = (i0 & 31) + r;   // query col
    float* Srow = S + r * kHW;
    const float* rwr = rw + r * 64;
    const float* rhr = rh + r * 64;
    float mx = -1e30f;
    for (int t = 0; t < 16; ++t) {
      const int j = lane + t * 64;
      const float s = Srow[j] + rwr[(j & 31) - yq + 31] + rhr[(j >> 5) - xq + 31];
      Srow[j] = s;
      mx = fmaxf(mx, s);
    }
#pragma unroll
    for (int off = 32; off; off >>= 1) mx = fmaxf(mx, __shfl_xor(mx, off));
    float sm = 0.f;
    for (int t = 0; t < 16; ++t) {
      const int j = lane + t * 64;
      const float p = __expf(Srow[j] - mx);
      Srow[j] = p;
      sm += p;
    }
#pragma unroll
    for (int off = 32; off; off >>= 1) sm += __shfl_xor(sm, off);
    rsum[mi] = sm;
  }

  // O[i][d] = sum_j p[i][j] * v[d][j], lane -> d, v staged transposed per chunk
  float oacc[4] = {};
  for (int jc = 0; jc < kHW; jc += 64) {
    __syncthreads();
    for (int e = tid; e < 4096; e += 256) {
      const int d = e >> 6, j = e & 63;
      vT[j * 65 + d] = v_[d * kHW + jc + j];
    }
    __syncthreads();
    for (int j4 = 0; j4 < 64; j4 += 4) {
      const float v0 = vT[(j4 + 0) * 65 + lane];
      const float v1 = vT[(j4 + 1) * 65 + lane];
      const float v2 = vT[(j4 + 2) * 65 + lane];
      const float v3 = vT[(j4 + 3) * 65 + lane];
#pragma unroll
      for (int mi = 0; mi < 4; ++mi) {
        const float4 p4 = *reinterpret_cast<const float4*>(&S[(ig * 4 + mi) * kHW + jc + j4]);
        oacc[mi] += p4.x * v0 + p4.y * v1 + p4.z * v2 + p4.w * v3;
      }
    }
  }
#pragma unroll
  for (int mi = 0; mi < 4; ++mi) {
    const int i = i0 + ig * 4 + mi;
    attn[(size_t)bn * 65536 + (size_t)i * 64 + lane] = oacc[mi] / rsum[mi];
  }
}

// ---------------------------------------------------------------------------
extern "C" void kernel_launch(void* const* d_in, const int* in_sizes, int n_in,
                              void* d_out, int out_size, void* d_ws, size_t ws_size,
                              hipStream_t stream) {
  const float* q_x = (const float*)d_in[0];
  const float* k_x = (const float*)d_in[1];
  const float* v_x = (const float*)d_in[2];
  const float* Wq  = (const float*)d_in[3];
  const float* bq  = (const float*)d_in[4];
  const float* Wk  = (const float*)d_in[5];
  const float* bk  = (const float*)d_in[6];
  const float* Wv  = (const float*)d_in[7];
  const float* bv  = (const float*)d_in[8];
  const float* Wo  = (const float*)d_in[9];
  const float* bo  = (const float*)d_in[10];
  const float* krw = (const float*)d_in[11];
  const float* krh = (const float*)d_in[12];

  float* ws  = (float*)d_ws;
  const size_t qkvSz = (size_t)kB * kO * kHW;  // 4,194,304 floats = 16 MB
  float* wsQ = ws;
  float* wsK = wsQ + qkvSz;
  float* wsV = wsK + qkvSz;
  float* wsA = wsV + qkvSz;                    // [B][512][1024] combined heads

  // projections: q scaled by DK^-0.5 = 0.125 (applied to conv output incl bias)
  conv1x1_k<<<dim3(16, 8, kB), 256, 0, stream>>>(q_x, Wq, bq, wsQ, kC, kO, 0.125f);
  conv1x1_k<<<dim3(16, 8, kB), 256, 0, stream>>>(k_x, Wk, bk, wsK, kC, kO, 1.0f);
  conv1x1_k<<<dim3(16, 8, kB), 256, 0, stream>>>(v_x, Wv, bv, wsV, kC, kO, 1.0f);

  // attention: 64 query tiles x 64 (b,nh)
  attn_k<<<dim3(64, 64), 256, 0, stream>>>(wsQ, wsK, wsV, krw, krh, wsA);

  // output projection
  conv1x1_k<<<dim3(16, 1, kB), 256, 0, stream>>>(wsA, Wo, bo, (float*)d_out, kO, kDV, 1.0f);
}

// Round 2
// 179.830 us; speedup vs baseline: 7.7532x; 7.7532x over previous
//
#include <hip/hip_runtime.h>

using f32x4  = __attribute__((ext_vector_type(4))) float;
using bf16x8 = __attribute__((ext_vector_type(8))) short;

constexpr int kC = 256, kHW = 1024;

__device__ __forceinline__ ushort f2bf(float f) {
  union { float f; unsigned u; } v{f};
  unsigned r = v.u + 0x7FFFu + ((v.u >> 16) & 1u);   // round-nearest-even
  return (ushort)(r >> 16);
}

__device__ __forceinline__ f32x4 mfma16(bf16x8 a, bf16x8 b, f32x4 c) {
  return __builtin_amdgcn_mfma_f32_16x16x32_bf16(a, b, c, 0, 0, 0);
}

// ---------------------------------------------------------------------------
// Projection -> bf16 [bn][hw][64]  (out^T GEMM: rows = hw, cols = o)
// ---------------------------------------------------------------------------
__global__ __launch_bounds__(256) void conv_qkT(
    const float* __restrict__ x, const float* __restrict__ Wm,
    const float* __restrict__ bias, ushort* __restrict__ out, float scale)
{
  __shared__ float sW[16][68];
  __shared__ float sX[16][64];
  const int b = blockIdx.z, o0 = blockIdx.y * 64, hw0 = blockIdx.x * 64;
  const float* xb = x + (size_t)b * kC * kHW;
  const int tid = threadIdx.x;
  const int tx = tid & 15, ty = tid >> 4;
  const int lm = tid >> 2, lk = (tid & 3) * 4;
  const int xk = tid >> 4, xn = (tid & 15) * 4;
  float acc[4][4] = {};
  for (int k0 = 0; k0 < kC; k0 += 16) {
    const float4 wv = *reinterpret_cast<const float4*>(&Wm[(size_t)(o0 + lm) * kC + k0 + lk]);
    const float4 xv = *reinterpret_cast<const float4*>(&xb[(size_t)(k0 + xk) * kHW + hw0 + xn]);
    __syncthreads();
    sW[lk + 0][lm] = wv.x; sW[lk + 1][lm] = wv.y;
    sW[lk + 2][lm] = wv.z; sW[lk + 3][lm] = wv.w;
    *reinterpret_cast<float4*>(&sX[xk][xn]) = xv;
    __syncthreads();
#pragma unroll
    for (int kk = 0; kk < 16; ++kk) {
      const float4 a4 = *reinterpret_cast<const float4*>(&sX[kk][ty * 4]);  // hw
      const float4 b4 = *reinterpret_cast<const float4*>(&sW[kk][tx * 4]);  // o
      const float am[4] = {a4.x, a4.y, a4.z, a4.w};
      const float bv[4] = {b4.x, b4.y, b4.z, b4.w};
#pragma unroll
      for (int mi = 0; mi < 4; ++mi)
#pragma unroll
        for (int ni = 0; ni < 4; ++ni) acc[mi][ni] += am[mi] * bv[ni];
    }
  }
  ushort* ob = out + (size_t)(b * 8 + blockIdx.y) * 65536;
  float bb[4];
#pragma unroll
  for (int ni = 0; ni < 4; ++ni) bb[ni] = bias[o0 + tx * 4 + ni];
#pragma unroll
  for (int mi = 0; mi < 4; ++mi) {
    const int hw = hw0 + ty * 4 + mi;
    ushort4 st;
    st.x = f2bf((acc[mi][0] + bb[0]) * scale);
    st.y = f2bf((acc[mi][1] + bb[1]) * scale);
    st.z = f2bf((acc[mi][2] + bb[2]) * scale);
    st.w = f2bf((acc[mi][3] + bb[3]) * scale);
    *reinterpret_cast<ushort4*>(&ob[(size_t)hw * 64 + tx * 4]) = st;
  }
}

// ---------------------------------------------------------------------------
// Projection -> bf16 [bn][d][hw]  (V)
// ---------------------------------------------------------------------------
__global__ __launch_bounds__(256) void conv_vT(
    const float* __restrict__ x, const float* __restrict__ Wm,
    const float* __restrict__ bias, ushort* __restrict__ out)
{
  __shared__ float sW[16][68];
  __shared__ float sX[16][64];
  const int b = blockIdx.z, o0 = blockIdx.y * 64, n0 = blockIdx.x * 64;
  const float* xb = x + (size_t)b * kC * kHW;
  const int tid = threadIdx.x;
  const int tx = tid & 15, ty = tid >> 4;
  const int lm = tid >> 2, lk = (tid & 3) * 4;
  const int xk = tid >> 4, xn = (tid & 15) * 4;
  float acc[4][4] = {};
  for (int k0 = 0; k0 < kC; k0 += 16) {
    const float4 wv = *reinterpret_cast<const float4*>(&Wm[(size_t)(o0 + lm) * kC + k0 + lk]);
    const float4 xv = *reinterpret_cast<const float4*>(&xb[(size_t)(k0 + xk) * kHW + n0 + xn]);
    __syncthreads();
    sW[lk + 0][lm] = wv.x; sW[lk + 1][lm] = wv.y;
    sW[lk + 2][lm] = wv.z; sW[lk + 3][lm] = wv.w;
    *reinterpret_cast<float4*>(&sX[xk][xn]) = xv;
    __syncthreads();
#pragma unroll
    for (int kk = 0; kk < 16; ++kk) {
      const float4 a4 = *reinterpret_cast<const float4*>(&sW[kk][ty * 4]);  // o
      const float4 b4 = *reinterpret_cast<const float4*>(&sX[kk][tx * 4]);  // hw
      const float am[4] = {a4.x, a4.y, a4.z, a4.w};
      const float bv[4] = {b4.x, b4.y, b4.z, b4.w};
#pragma unroll
      for (int mi = 0; mi < 4; ++mi)
#pragma unroll
        for (int ni = 0; ni < 4; ++ni) acc[mi][ni] += am[mi] * bv[ni];
    }
  }
  ushort* ob = out + (size_t)(b * 8 + blockIdx.y) * 65536;
#pragma unroll
  for (int mi = 0; mi < 4; ++mi) {
    const float bb = bias[o0 + ty * 4 + mi];
    ushort4 st;
    st.x = f2bf(acc[mi][0] + bb);
    st.y = f2bf(acc[mi][1] + bb);
    st.z = f2bf(acc[mi][2] + bb);
    st.w = f2bf(acc[mi][3] + bb);
    *reinterpret_cast<ushort4*>(&ob[(size_t)(ty * 4 + mi) * 1024 + n0 + tx * 4]) = st;
  }
}

// ---------------------------------------------------------------------------
// fp32 conv (output projection): out[b][o][hw]
// ---------------------------------------------------------------------------
__global__ __launch_bounds__(256) void conv1x1_k(
    const float* __restrict__ x, const float* __restrict__ Wm,
    const float* __restrict__ bias, float* __restrict__ out,
    int Cdim, int Odim)
{
  __shared__ float sW[16][68];
  __shared__ float sX[16][64];
  const int b = blockIdx.z, o0 = blockIdx.y * 64, n0 = blockIdx.x * 64;
  const float* xb = x + (size_t)b * Cdim * kHW;
  float* ob = out + (size_t)b * Odim * kHW;
  const int tid = threadIdx.x;
  const int tx = tid & 15, ty = tid >> 4;
  const int lm = tid >> 2, lk = (tid & 3) * 4;
  const int xk = tid >> 4, xn = (tid & 15) * 4;
  float acc[4][4] = {};
  for (int k0 = 0; k0 < Cdim; k0 += 16) {
    const float4 wv = *reinterpret_cast<const float4*>(&Wm[(size_t)(o0 + lm) * Cdim + k0 + lk]);
    const float4 xv = *reinterpret_cast<const float4*>(&xb[(size_t)(k0 + xk) * kHW + n0 + xn]);
    __syncthreads();
    sW[lk + 0][lm] = wv.x; sW[lk + 1][lm] = wv.y;
    sW[lk + 2][lm] = wv.z; sW[lk + 3][lm] = wv.w;
    *reinterpret_cast<float4*>(&sX[xk][xn]) = xv;
    __syncthreads();
#pragma unroll
    for (int kk = 0; kk < 16; ++kk) {
      const float4 a4 = *reinterpret_cast<const float4*>(&sW[kk][ty * 4]);
      const float4 b4 = *reinterpret_cast<const float4*>(&sX[kk][tx * 4]);
      const float am[4] = {a4.x, a4.y, a4.z, a4.w};
      const float bv[4] = {b4.x, b4.y, b4.z, b4.w};
#pragma unroll
      for (int mi = 0; mi < 4; ++mi)
#pragma unroll
        for (int ni = 0; ni < 4; ++ni) acc[mi][ni] += am[mi] * bv[ni];
    }
  }
#pragma unroll
  for (int mi = 0; mi < 4; ++mi) {
    const int o = o0 + ty * 4 + mi;
    const float bb = bias[o];
    float4 r = {acc[mi][0] + bb, acc[mi][1] + bb, acc[mi][2] + bb, acc[mi][3] + bb};
    *reinterpret_cast<float4*>(&ob[(size_t)o * kHW + n0 + tx * 4]) = r;
  }
}

// ---------------------------------------------------------------------------
// MFMA flash attention. Block = (bn, 64 queries), 4 waves x 16 q-rows.
// Swapped QK^T: S^T = mfma(K, Q) -> lane owns one query row (i = lane&15).
// rel logits: rw via 8 preloaded regs (j&31 pattern repeats per 64-chunk),
// rh via 2 LDS reads per chunk. P transposed through wave-private LDS.
// ---------------------------------------------------------------------------
__global__ __launch_bounds__(256) void attn_mfma(
    const ushort* __restrict__ qg, const ushort* __restrict__ kg,
    const ushort* __restrict__ vg, const float* __restrict__ relw,
    const float* __restrict__ relh, float* __restrict__ attn)
{
  __shared__ ushort Klds[64 * 72];       // [j][d], stride 144B
  __shared__ ushort Vlds[64 * 72];       // [dv][j]
  __shared__ ushort Plds[4][16 * 72];    // per-wave [i][j]
  __shared__ float  rwlds[4][16 * 65];   // per-wave [i][m]
  __shared__ float  rhlds[4][16 * 65];

  const int bn = blockIdx.y;
  const int qb = blockIdx.x * 64;
  const int tid = threadIdx.x;
  const int w = tid >> 6, lane = tid & 63;
  const int li = lane & 15, g = lane >> 4;

  const ushort* qbn = qg + (size_t)bn * 65536;
  const ushort* kbn = kg + (size_t)bn * 65536;
  const ushort* vbn = vg + (size_t)bn * 65536;

  const int srow = tid >> 3;   // 0..31
  const int sseg = tid & 7;    // 0..7

  // prefetch chunk 0 into regs
  uint4 kst0 = *reinterpret_cast<const uint4*>(&kbn[(srow) * 64 + sseg * 8]);
  uint4 kst1 = *reinterpret_cast<const uint4*>(&kbn[(32 + srow) * 64 + sseg * 8]);
  uint4 vst0 = *reinterpret_cast<const uint4*>(&vbn[srow * 1024 + sseg * 8]);
  uint4 vst1 = *reinterpret_cast<const uint4*>(&vbn[(32 + srow) * 1024 + sseg * 8]);

  // Q fragments (lane holds q[i=li][d0..d0+7], d0 = g*8 (+32))
  const int qi = qb + w * 16 + li;
  const bf16x8 qf0 = *reinterpret_cast<const bf16x8*>(&qbn[qi * 64 + g * 8]);
  const bf16x8 qf1 = *reinterpret_cast<const bf16x8*>(&qbn[qi * 64 + 32 + g * 8]);

  // relative tables via MFMA (per-wave, wave-private)
  float* rwp = rwlds[w];
  float* rhp = rhlds[w];
#pragma unroll
  for (int tbl = 0; tbl < 2; ++tbl) {
    const float* rk = tbl ? relh : relw;
    float* dst = tbl ? rhp : rwp;
#pragma unroll
    for (int sub = 0; sub < 4; ++sub) {
      const int m = sub * 16 + li;
      const int mm = (m < 63) ? m : 0;
      bf16x8 b0, b1;
#pragma unroll
      for (int e = 0; e < 8; ++e) {
        b0[e] = (short)f2bf(rk[mm * 64 + g * 8 + e]);
        b1[e] = (short)f2bf(rk[mm * 64 + 32 + g * 8 + e]);
      }
      f32x4 d = {0.f, 0.f, 0.f, 0.f};
      d = mfma16(qf0, b0, d);
      d = mfma16(qf1, b1, d);
      if (m < 63) {
#pragma unroll
        for (int r = 0; r < 4; ++r) dst[(g * 4 + r) * 65 + m] = d[r];
      }
    }
  }

  // preload the 8 rw values this lane ever needs (j&31 pattern repeats)
  const int yq = qi & 31, xq = qi >> 5;
  float rwv[2][4];
#pragma unroll
  for (int p = 0; p < 2; ++p)
#pragma unroll
    for (int r = 0; r < 4; ++r)
      rwv[p][r] = rwp[li * 65 + (p * 16 + g * 4 + r - yq + 31)];

  f32x4 oacc[4];
#pragma unroll
  for (int sub = 0; sub < 4; ++sub) oacc[sub] = f32x4{0.f, 0.f, 0.f, 0.f};
  float mrun = -1e30f, lrun = 0.f;
  ushort* Pw = Plds[w];

  for (int c = 0; c < 16; ++c) {
    __syncthreads();
    *reinterpret_cast<uint4*>(&Klds[srow * 72 + sseg * 8]) = kst0;
    *reinterpret_cast<uint4*>(&Klds[(32 + srow) * 72 + sseg * 8]) = kst1;
    *reinterpret_cast<uint4*>(&Vlds[srow * 72 + sseg * 8]) = vst0;
    *reinterpret_cast<uint4*>(&Vlds[(32 + srow) * 72 + sseg * 8]) = vst1;
    __syncthreads();
    if (c < 15) {
      const int jc = (c + 1) * 64;
      kst0 = *reinterpret_cast<const uint4*>(&kbn[(jc + srow) * 64 + sseg * 8]);
      kst1 = *reinterpret_cast<const uint4*>(&kbn[(jc + 32 + srow) * 64 + sseg * 8]);
      vst0 = *reinterpret_cast<const uint4*>(&vbn[srow * 1024 + jc + sseg * 8]);
      vst1 = *reinterpret_cast<const uint4*>(&vbn[(32 + srow) * 1024 + jc + sseg * 8]);
    }

    // S^T chunk: rows j = sub*16 + g*4 + r, col i = li (this lane's query)
    f32x4 s[4];
#pragma unroll
    for (int sub = 0; sub < 4; ++sub) {
      const bf16x8 ka0 = *reinterpret_cast<const bf16x8*>(&Klds[(sub * 16 + li) * 72 + g * 8]);
      const bf16x8 ka1 = *reinterpret_cast<const bf16x8*>(&Klds[(sub * 16 + li) * 72 + 32 + g * 8]);
      f32x4 d = {0.f, 0.f, 0.f, 0.f};
      d = mfma16(ka0, qf0, d);
      d = mfma16(ka1, qf1, d);
      s[sub] = d;
    }

    // relative logits
    const float rh0 = rhp[li * 65 + (c * 2 + 0 - xq + 31)];
    const float rh1 = rhp[li * 65 + (c * 2 + 1 - xq + 31)];
#pragma unroll
    for (int sub = 0; sub < 4; ++sub) {
      const float rhx = (sub < 2) ? rh0 : rh1;
#pragma unroll
      for (int r = 0; r < 4; ++r) s[sub][r] += rwv[sub & 1][r] + rhx;
    }

    // online softmax (row = query li; combine 4 lane-groups via shfl)
    float cmax = s[0][0];
#pragma unroll
    for (int sub = 0; sub < 4; ++sub)
#pragma unroll
      for (int r = 0; r < 4; ++r) cmax = fmaxf(cmax, s[sub][r]);
    cmax = fmaxf(cmax, __shfl_xor(cmax, 16));
    cmax = fmaxf(cmax, __shfl_xor(cmax, 32));
    const float mnew = fmaxf(mrun, cmax);
    const float fsc = __expf(mrun - mnew);
    mrun = mnew;
    float psum = 0.f;
    float p[4][4];
#pragma unroll
    for (int sub = 0; sub < 4; ++sub)
#pragma unroll
      for (int r = 0; r < 4; ++r) {
        const float pv = __expf(s[sub][r] - mnew);
        p[sub][r] = pv;
        psum += pv;
      }
    lrun = lrun * fsc + psum;

    // P -> bf16 -> wave-private LDS (row li, cols j)
#pragma unroll
    for (int sub = 0; sub < 4; ++sub) {
      uint2 pk;
      pk.x = (uint)f2bf(p[sub][0]) | ((uint)f2bf(p[sub][1]) << 16);
      pk.y = (uint)f2bf(p[sub][2]) | ((uint)f2bf(p[sub][3]) << 16);
      *reinterpret_cast<uint2*>(&Pw[li * 72 + sub * 16 + g * 4]) = pk;
    }

    // rescale O accumulators (rows i = g*4+r need factor from lane g*4+r)
    float fr[4];
#pragma unroll
    for (int r = 0; r < 4; ++r) fr[r] = __shfl(fsc, g * 4 + r);
#pragma unroll
    for (int sub = 0; sub < 4; ++sub)
#pragma unroll
      for (int r = 0; r < 4; ++r) oacc[sub][r] *= fr[r];

    // PV: O[i][dv] += P[i][j] * V[dv][j]
#pragma unroll
    for (int step = 0; step < 2; ++step) {
      const bf16x8 pa = *reinterpret_cast<const bf16x8*>(&Pw[li * 72 + step * 32 + g * 8]);
#pragma unroll
      for (int sub = 0; sub < 4; ++sub) {
        const bf16x8 vb = *reinterpret_cast<const bf16x8*>(&Vlds[(sub * 16 + li) * 72 + step * 32 + g * 8]);
        oacc[sub] = mfma16(pa, vb, oacc[sub]);
      }
    }
  }

  // finalize: total row sum, divide, store
  float lt = lrun + __shfl_xor(lrun, 16);
  lt = lt + __shfl_xor(lt, 32);
  float linv[4];
#pragma unroll
  for (int r = 0; r < 4; ++r) linv[r] = 1.0f / __shfl(lt, g * 4 + r);
  float* ob = attn + (size_t)bn * 65536;
#pragma unroll
  for (int sub = 0; sub < 4; ++sub)
#pragma unroll
    for (int r = 0; r < 4; ++r)
      ob[(size_t)(qb + w * 16 + g * 4 + r) * 64 + sub * 16 + li] = oacc[sub][r] * linv[r];
}

// ---------------------------------------------------------------------------
extern "C" void kernel_launch(void* const* d_in, const int* in_sizes, int n_in,
                              void* d_out, int out_size, void* d_ws, size_t ws_size,
                              hipStream_t stream) {
  const float* q_x = (const float*)d_in[0];
  const float* k_x = (const float*)d_in[1];
  const float* v_x = (const float*)d_in[2];
  const float* Wq  = (const float*)d_in[3];
  const float* bq  = (const float*)d_in[4];
  const float* Wk  = (const float*)d_in[5];
  const float* bk  = (const float*)d_in[6];
  const float* Wv  = (const float*)d_in[7];
  const float* bv  = (const float*)d_in[8];
  const float* Wo  = (const float*)d_in[9];
  const float* bo  = (const float*)d_in[10];
  const float* krw = (const float*)d_in[11];
  const float* krh = (const float*)d_in[12];

  ushort* wsQ = (ushort*)d_ws;                 // [64][1024][64] bf16
  ushort* wsK = wsQ + 4194304;                 // [64][1024][64] bf16
  ushort* wsV = wsK + 4194304;                 // [64][64][1024] bf16
  float*  wsA = (float*)(wsV + 4194304);       // [8][512][1024] fp32

  conv_qkT<<<dim3(16, 8, 8), 256, 0, stream>>>(q_x, Wq, bq, wsQ, 0.125f);
  conv_qkT<<<dim3(16, 8, 8), 256, 0, stream>>>(k_x, Wk, bk, wsK, 1.0f);
  conv_vT <<<dim3(16, 8, 8), 256, 0, stream>>>(v_x, Wv, bv, wsV);

  attn_mfma<<<dim3(16, 64), 256, 0, stream>>>(wsQ, wsK, wsV, krw, krh, wsA);

  conv1x1_k<<<dim3(16, 1, 8), 256, 0, stream>>>(wsA, Wo, bo, (float*)d_out, 512, 64);
}

// Round 3
// 130.958 us; speedup vs baseline: 10.6466x; 1.3732x over previous
//
#include <hip/hip_runtime.h>

using f32x4  = __attribute__((ext_vector_type(4))) float;
using bf16x8 = __attribute__((ext_vector_type(8))) short;

__device__ __forceinline__ ushort f2bf(float f) {
  union { float f; unsigned u; } v{f};
  unsigned r = v.u + 0x7FFFu + ((v.u >> 16) & 1u);   // round-nearest-even
  return (ushort)(r >> 16);
}
__device__ __forceinline__ ushort4 f4bf(float4 f) {
  ushort4 r; r.x = f2bf(f.x); r.y = f2bf(f.y); r.z = f2bf(f.z); r.w = f2bf(f.w); return r;
}
__device__ __forceinline__ f32x4 mfma16(bf16x8 a, bf16x8 b, f32x4 c) {
  return __builtin_amdgcn_mfma_f32_16x16x32_bf16(a, b, c, 0, 0, 0);
}

// ---------------------------------------------------------------------------
// prep_T: x[b][c][hw] fp32 -> xT[inp][b][hw][c] bf16 (64x64 LDS tile transpose)
// ---------------------------------------------------------------------------
__global__ __launch_bounds__(256) void prep_T(
    const float* __restrict__ x0, const float* __restrict__ x1,
    const float* __restrict__ x2, ushort* __restrict__ xT)
{
  __shared__ ushort sT[64 * 72];
  const int t = threadIdx.x;
  const int inp = blockIdx.y >> 2, c0 = (blockIdx.y & 3) * 64;
  const int b = blockIdx.z, hw0 = blockIdx.x * 64;
  const float* src = (inp == 0 ? x0 : inp == 1 ? x1 : x2) +
                     ((size_t)b * 256 + c0) * 1024 + hw0;
  const int clb = t >> 4, hwl = (t & 15) * 4;
#pragma unroll
  for (int cc = 0; cc < 4; ++cc) {
    const int cl = clb + cc * 16;
    const float4 v = *reinterpret_cast<const float4*>(&src[(size_t)cl * 1024 + hwl]);
    *reinterpret_cast<ushort4*>(&sT[cl * 72 + hwl]) = f4bf(v);
  }
  __syncthreads();
  const int hv = t >> 2, cs = (t & 3) * 16;
  ushort tmp[16];
#pragma unroll
  for (int j = 0; j < 16; ++j) tmp[j] = sT[(cs + j) * 72 + hv];
  ushort* dst = xT + (size_t)inp * 2097152 +
                ((size_t)b * 1024 + hw0 + hv) * 256 + c0 + cs;
  *reinterpret_cast<uint4*>(&dst[0]) = *reinterpret_cast<uint4*>(&tmp[0]);
  *reinterpret_cast<uint4*>(&dst[8]) = *reinterpret_cast<uint4*>(&tmp[8]);
}

// ---------------------------------------------------------------------------
// prep_W: Wq|Wk|Wv|Wo fp32 -> contiguous bf16 (131072 x3 + 32768 elems)
// ---------------------------------------------------------------------------
__global__ __launch_bounds__(256) void prep_W(
    const float* __restrict__ Wq, const float* __restrict__ Wk,
    const float* __restrict__ Wv, const float* __restrict__ Wo,
    ushort* __restrict__ dst)
{
  const int idx = (blockIdx.x * 256 + threadIdx.x) * 8;
  const int r = idx >> 17;
  const float* src = (r == 0 ? Wq : r == 1 ? Wk : r == 2 ? Wv : Wo) + (idx - r * 131072);
  const float4 a = *reinterpret_cast<const float4*>(&src[0]);
  const float4 b = *reinterpret_cast<const float4*>(&src[4]);
  ushort tmp[8];
  *reinterpret_cast<ushort4*>(&tmp[0]) = f4bf(a);
  *reinterpret_cast<ushort4*>(&tmp[4]) = f4bf(b);
  *reinterpret_cast<uint4*>(&dst[idx]) = *reinterpret_cast<uint4*>(&tmp[0]);
}

// ---------------------------------------------------------------------------
// conv_mfma<MODE>: out = W(512x256) . x(256x1024) + bias, bf16 MFMA.
// Tile: 64 hw x 256 o, K-steps of 32, 4 waves (each 64 o). 256 blocks.
// MODE 0: out[bn][hw][64] (Q/K, D rows = hw); MODE 1: out[bn][d][1024] (V).
// LDS-bounce epilogue for coalesced uint4 global writes.
// ---------------------------------------------------------------------------
template <int MODE>
__global__ __launch_bounds__(256) void conv_mfma(
    const ushort* __restrict__ xT,   // [b][1024][256] bf16
    const ushort* __restrict__ Wb,   // [512][256] bf16
    const float* __restrict__ bias,
    ushort* __restrict__ out, float scale)
{
  __shared__ ushort lds[MODE == 1 ? 18432 : 16896];
  const int t = threadIdx.x, w = t >> 6, lane = t & 63;
  const int li = lane & 15, g = lane >> 4;
  const int b = blockIdx.z, o0 = blockIdx.y * 256, hw0 = blockIdx.x * 64;
  const ushort* xb = xT + ((size_t)b * 1024 + hw0) * 256;
  const ushort* wb = Wb + (size_t)o0 * 256;
  const int srow = t >> 2, sseg = t & 3;

  f32x4 acc[4][4];
#pragma unroll
  for (int i = 0; i < 4; ++i)
#pragma unroll
    for (int j = 0; j < 4; ++j) acc[i][j] = f32x4{0.f, 0.f, 0.f, 0.f};

  for (int ks = 0; ks < 8; ++ks) {
    const int k0 = ks * 32;
    __syncthreads();
    // stage xT tile: 64 rows x 32 k, stride 40
    *reinterpret_cast<uint4*>(&lds[srow * 40 + sseg * 8]) =
        *reinterpret_cast<const uint4*>(&xb[(size_t)srow * 256 + k0 + sseg * 8]);
    // stage W tile: 256 rows x 32 k
#pragma unroll
    for (int it = 0; it < 4; ++it) {
      const int r = srow + it * 64;
      *reinterpret_cast<uint4*>(&lds[(64 + r) * 40 + sseg * 8]) =
          *reinterpret_cast<const uint4*>(&wb[(size_t)r * 256 + k0 + sseg * 8]);
    }
    __syncthreads();
    bf16x8 af[4], bf[4];
#pragma unroll
    for (int mi = 0; mi < 4; ++mi) {
      const int ra = (MODE == 0) ? (mi * 16 + li) : (64 + w * 64 + mi * 16 + li);
      af[mi] = *reinterpret_cast<const bf16x8*>(&lds[ra * 40 + g * 8]);
    }
#pragma unroll
    for (int ni = 0; ni < 4; ++ni) {
      const int rb = (MODE == 0) ? (64 + w * 64 + ni * 16 + li) : (ni * 16 + li);
      bf[ni] = *reinterpret_cast<const bf16x8*>(&lds[rb * 40 + g * 8]);
    }
#pragma unroll
    for (int mi = 0; mi < 4; ++mi)
#pragma unroll
      for (int ni = 0; ni < 4; ++ni)
        acc[mi][ni] = mfma16(af[mi], bf[ni], acc[mi][ni]);
  }
  __syncthreads();

  if (MODE == 0) {
    // rows = hw (mi*16 + g*4 + r), cols = o (w*64 + ni*16 + li)
    float bb[4];
#pragma unroll
    for (int ni = 0; ni < 4; ++ni) bb[ni] = bias[o0 + w * 64 + ni * 16 + li];
#pragma unroll
    for (int mi = 0; mi < 4; ++mi)
#pragma unroll
      for (int ni = 0; ni < 4; ++ni)
#pragma unroll
        for (int r = 0; r < 4; ++r)
          lds[(mi * 16 + g * 4 + r) * 264 + w * 64 + ni * 16 + li] =
              f2bf((acc[mi][ni][r] + bb[ni]) * scale);
    __syncthreads();
    const int row = t & 63;
    ushort* dst = out + (size_t)(b * 8 + (o0 >> 6) + w) * 65536 +
                  (size_t)(hw0 + row) * 64;
#pragma unroll
    for (int seg = 0; seg < 8; ++seg)
      *reinterpret_cast<uint4*>(&dst[seg * 8]) =
          *reinterpret_cast<const uint4*>(&lds[row * 264 + w * 64 + seg * 8]);
  } else {
    // rows = o (w*64 + mi*16 + g*4 + r), cols = hw (ni*16 + li)
#pragma unroll
    for (int mi = 0; mi < 4; ++mi)
#pragma unroll
      for (int r = 0; r < 4; ++r) {
        const float bb = bias[o0 + w * 64 + mi * 16 + g * 4 + r];
#pragma unroll
        for (int ni = 0; ni < 4; ++ni)
          lds[w * 4608 + (mi * 16 + g * 4 + r) * 72 + ni * 16 + li] =
              f2bf(acc[mi][ni][r] + bb);
      }
    __syncthreads();
    const int d = t & 63;
    ushort* dst = out + (size_t)(b * 8 + (o0 >> 6) + w) * 65536 +
                  (size_t)d * 1024 + hw0;
#pragma unroll
    for (int seg = 0; seg < 8; ++seg)
      *reinterpret_cast<uint4*>(&dst[seg * 8]) =
          *reinterpret_cast<const uint4*>(&lds[w * 4608 + d * 72 + seg * 8]);
  }
}

// ---------------------------------------------------------------------------
// outconv: out[b][64][1024] fp32 = Wo(64x512) . attnF(512x1024) + bo.
// B staged via fused fp32->bf16 transpose with XOR-swizzled columns.
// ---------------------------------------------------------------------------
__global__ __launch_bounds__(256) void outconv_mfma(
    const float* __restrict__ attnF,   // [8][512][1024] fp32
    const ushort* __restrict__ Wob,    // [64][512] bf16
    const float* __restrict__ bias,
    float* __restrict__ out)
{
  __shared__ float ldsf[64 * 68];                       // 17408 B bounce
  ushort* lds = reinterpret_cast<ushort*>(ldsf);        // stage: A [0,2560) B [2560,5120)
  const int t = threadIdx.x, w = t >> 6, lane = t & 63;
  const int li = lane & 15, g = lane >> 4;
  const int b = blockIdx.y, hw0 = blockIdx.x * 64;
  f32x4 acc[4];
#pragma unroll
  for (int i = 0; i < 4; ++i) acc[i] = f32x4{0.f, 0.f, 0.f, 0.f};

  for (int ks = 0; ks < 16; ++ks) {
    const int k0 = ks * 32;
    __syncthreads();
    *reinterpret_cast<uint4*>(&lds[(t >> 2) * 40 + (t & 3) * 8]) =
        *reinterpret_cast<const uint4*>(&Wob[(size_t)(t >> 2) * 512 + k0 + (t & 3) * 8]);
#pragma unroll
    for (int it = 0; it < 2; ++it) {
      const int c = (t >> 4) + it * 16;
      const float4 v = *reinterpret_cast<const float4*>(
          &attnF[((size_t)b * 512 + k0 + c) * 1024 + hw0 + (t & 15) * 4]);
      const int swz = c ^ ((t & 3) << 3);     // row = 4*(t&15)+j -> (row>>2)&3 == t&3
      const float vv[4] = {v.x, v.y, v.z, v.w};
#pragma unroll
      for (int j = 0; j < 4; ++j)
        lds[2560 + ((t & 15) * 4 + j) * 40 + swz] = f2bf(vv[j]);
    }
    __syncthreads();
    const bf16x8 bfg = *reinterpret_cast<const bf16x8*>(
        &lds[2560 + (w * 16 + li) * 40 + 8 * (g ^ ((li >> 2) & 3))]);
#pragma unroll
    for (int mi = 0; mi < 4; ++mi) {
      const bf16x8 af = *reinterpret_cast<const bf16x8*>(&lds[(mi * 16 + li) * 40 + g * 8]);
      acc[mi] = mfma16(af, bfg, acc[mi]);
    }
  }
  __syncthreads();
#pragma unroll
  for (int mi = 0; mi < 4; ++mi)
#pragma unroll
    for (int r = 0; r < 4; ++r)
      ldsf[(mi * 16 + g * 4 + r) * 68 + w * 16 + li] =
          acc[mi][r] + bias[mi * 16 + g * 4 + r];
  __syncthreads();
  const int o = t >> 2, cs = (t & 3) * 16;
  float* dst = out + ((size_t)b * 64 + o) * 1024 + hw0;
#pragma unroll
  for (int f = 0; f < 4; ++f)
    *reinterpret_cast<float4*>(&dst[cs + f * 4]) =
        *reinterpret_cast<const float4*>(&ldsf[o * 68 + cs + f * 4]);
}

// ---------------------------------------------------------------------------
// MFMA flash attention (UNCHANGED from round 2).
// ---------------------------------------------------------------------------
__global__ __launch_bounds__(256) void attn_mfma(
    const ushort* __restrict__ qg, const ushort* __restrict__ kg,
    const ushort* __restrict__ vg, const float* __restrict__ relw,
    const float* __restrict__ relh, float* __restrict__ attn)
{
  __shared__ ushort Klds[64 * 72];       // [j][d], stride 144B
  __shared__ ushort Vlds[64 * 72];       // [dv][j]
  __shared__ ushort Plds[4][16 * 72];    // per-wave [i][j]
  __shared__ float  rwlds[4][16 * 65];   // per-wave [i][m]
  __shared__ float  rhlds[4][16 * 65];

  const int bn = blockIdx.y;
  const int qb = blockIdx.x * 64;
  const int tid = threadIdx.x;
  const int w = tid >> 6, lane = tid & 63;
  const int li = lane & 15, g = lane >> 4;

  const ushort* qbn = qg + (size_t)bn * 65536;
  const ushort* kbn = kg + (size_t)bn * 65536;
  const ushort* vbn = vg + (size_t)bn * 65536;

  const int srow = tid >> 3;   // 0..31
  const int sseg = tid & 7;    // 0..7

  uint4 kst0 = *reinterpret_cast<const uint4*>(&kbn[(srow) * 64 + sseg * 8]);
  uint4 kst1 = *reinterpret_cast<const uint4*>(&kbn[(32 + srow) * 64 + sseg * 8]);
  uint4 vst0 = *reinterpret_cast<const uint4*>(&vbn[srow * 1024 + sseg * 8]);
  uint4 vst1 = *reinterpret_cast<const uint4*>(&vbn[(32 + srow) * 1024 + sseg * 8]);

  const int qi = qb + w * 16 + li;
  const bf16x8 qf0 = *reinterpret_cast<const bf16x8*>(&qbn[qi * 64 + g * 8]);
  const bf16x8 qf1 = *reinterpret_cast<const bf16x8*>(&qbn[qi * 64 + 32 + g * 8]);

  float* rwp = rwlds[w];
  float* rhp = rhlds[w];
#pragma unroll
  for (int tbl = 0; tbl < 2; ++tbl) {
    const float* rk = tbl ? relh : relw;
    float* dst = tbl ? rhp : rwp;
#pragma unroll
    for (int sub = 0; sub < 4; ++sub) {
      const int m = sub * 16 + li;
      const int mm = (m < 63) ? m : 0;
      bf16x8 b0, b1;
#pragma unroll
      for (int e = 0; e < 8; ++e) {
        b0[e] = (short)f2bf(rk[mm * 64 + g * 8 + e]);
        b1[e] = (short)f2bf(rk[mm * 64 + 32 + g * 8 + e]);
      }
      f32x4 d = {0.f, 0.f, 0.f, 0.f};
      d = mfma16(qf0, b0, d);
      d = mfma16(qf1, b1, d);
      if (m < 63) {
#pragma unroll
        for (int r = 0; r < 4; ++r) dst[(g * 4 + r) * 65 + m] = d[r];
      }
    }
  }

  const int yq = qi & 31, xq = qi >> 5;
  float rwv[2][4];
#pragma unroll
  for (int p = 0; p < 2; ++p)
#pragma unroll
    for (int r = 0; r < 4; ++r)
      rwv[p][r] = rwp[li * 65 + (p * 16 + g * 4 + r - yq + 31)];

  f32x4 oacc[4];
#pragma unroll
  for (int sub = 0; sub < 4; ++sub) oacc[sub] = f32x4{0.f, 0.f, 0.f, 0.f};
  float mrun = -1e30f, lrun = 0.f;
  ushort* Pw = Plds[w];

  for (int c = 0; c < 16; ++c) {
    __syncthreads();
    *reinterpret_cast<uint4*>(&Klds[srow * 72 + sseg * 8]) = kst0;
    *reinterpret_cast<uint4*>(&Klds[(32 + srow) * 72 + sseg * 8]) = kst1;
    *reinterpret_cast<uint4*>(&Vlds[srow * 72 + sseg * 8]) = vst0;
    *reinterpret_cast<uint4*>(&Vlds[(32 + srow) * 72 + sseg * 8]) = vst1;
    __syncthreads();
    if (c < 15) {
      const int jc = (c + 1) * 64;
      kst0 = *reinterpret_cast<const uint4*>(&kbn[(jc + srow) * 64 + sseg * 8]);
      kst1 = *reinterpret_cast<const uint4*>(&kbn[(jc + 32 + srow) * 64 + sseg * 8]);
      vst0 = *reinterpret_cast<const uint4*>(&vbn[srow * 1024 + jc + sseg * 8]);
      vst1 = *reinterpret_cast<const uint4*>(&vbn[(32 + srow) * 1024 + jc + sseg * 8]);
    }

    f32x4 s[4];
#pragma unroll
    for (int sub = 0; sub < 4; ++sub) {
      const bf16x8 ka0 = *reinterpret_cast<const bf16x8*>(&Klds[(sub * 16 + li) * 72 + g * 8]);
      const bf16x8 ka1 = *reinterpret_cast<const bf16x8*>(&Klds[(sub * 16 + li) * 72 + 32 + g * 8]);
      f32x4 d = {0.f, 0.f, 0.f, 0.f};
      d = mfma16(ka0, qf0, d);
      d = mfma16(ka1, qf1, d);
      s[sub] = d;
    }

    const float rh0 = rhp[li * 65 + (c * 2 + 0 - xq + 31)];
    const float rh1 = rhp[li * 65 + (c * 2 + 1 - xq + 31)];
#pragma unroll
    for (int sub = 0; sub < 4; ++sub) {
      const float rhx = (sub < 2) ? rh0 : rh1;
#pragma unroll
      for (int r = 0; r < 4; ++r) s[sub][r] += rwv[sub & 1][r] + rhx;
    }

    float cmax = s[0][0];
#pragma unroll
    for (int sub = 0; sub < 4; ++sub)
#pragma unroll
      for (int r = 0; r < 4; ++r) cmax = fmaxf(cmax, s[sub][r]);
    cmax = fmaxf(cmax, __shfl_xor(cmax, 16));
    cmax = fmaxf(cmax, __shfl_xor(cmax, 32));
    const float mnew = fmaxf(mrun, cmax);
    const float fsc = __expf(mrun - mnew);
    mrun = mnew;
    float psum = 0.f;
    float p[4][4];
#pragma unroll
    for (int sub = 0; sub < 4; ++sub)
#pragma unroll
      for (int r = 0; r < 4; ++r) {
        const float pv = __expf(s[sub][r] - mnew);
        p[sub][r] = pv;
        psum += pv;
      }
    lrun = lrun * fsc + psum;

#pragma unroll
    for (int sub = 0; sub < 4; ++sub) {
      uint2 pk;
      pk.x = (uint)f2bf(p[sub][0]) | ((uint)f2bf(p[sub][1]) << 16);
      pk.y = (uint)f2bf(p[sub][2]) | ((uint)f2bf(p[sub][3]) << 16);
      *reinterpret_cast<uint2*>(&Pw[li * 72 + sub * 16 + g * 4]) = pk;
    }

    float fr[4];
#pragma unroll
    for (int r = 0; r < 4; ++r) fr[r] = __shfl(fsc, g * 4 + r);
#pragma unroll
    for (int sub = 0; sub < 4; ++sub)
#pragma unroll
      for (int r = 0; r < 4; ++r) oacc[sub][r] *= fr[r];

#pragma unroll
    for (int step = 0; step < 2; ++step) {
      const bf16x8 pa = *reinterpret_cast<const bf16x8*>(&Pw[li * 72 + step * 32 + g * 8]);
#pragma unroll
      for (int sub = 0; sub < 4; ++sub) {
        const bf16x8 vb = *reinterpret_cast<const bf16x8*>(&Vlds[(sub * 16 + li) * 72 + step * 32 + g * 8]);
        oacc[sub] = mfma16(pa, vb, oacc[sub]);
      }
    }
  }

  float lt = lrun + __shfl_xor(lrun, 16);
  lt = lt + __shfl_xor(lt, 32);
  float linv[4];
#pragma unroll
  for (int r = 0; r < 4; ++r) linv[r] = 1.0f / __shfl(lt, g * 4 + r);
  float* ob = attn + (size_t)bn * 65536;
#pragma unroll
  for (int sub = 0; sub < 4; ++sub)
#pragma unroll
    for (int r = 0; r < 4; ++r)
      ob[(size_t)(qb + w * 16 + g * 4 + r) * 64 + sub * 16 + li] = oacc[sub][r] * linv[r];
}

// ---------------------------------------------------------------------------
extern "C" void kernel_launch(void* const* d_in, const int* in_sizes, int n_in,
                              void* d_out, int out_size, void* d_ws, size_t ws_size,
                              hipStream_t stream) {
  const float* q_x = (const float*)d_in[0];
  const float* k_x = (const float*)d_in[1];
  const float* v_x = (const float*)d_in[2];
  const float* Wq  = (const float*)d_in[3];
  const float* bq  = (const float*)d_in[4];
  const float* Wk  = (const float*)d_in[5];
  const float* bk  = (const float*)d_in[6];
  const float* Wv  = (const float*)d_in[7];
  const float* bv  = (const float*)d_in[8];
  const float* Wo  = (const float*)d_in[9];
  const float* bo  = (const float*)d_in[10];
  const float* krw = (const float*)d_in[11];
  const float* krh = (const float*)d_in[12];

  ushort* wsQ  = (ushort*)d_ws;                 // [64][1024][64] bf16   8 MB
  ushort* wsK  = wsQ + 4194304;                 // 8 MB
  ushort* wsV  = wsK + 4194304;                 // [64][64][1024] bf16   8 MB
  ushort* xT   = wsV + 4194304;                 // 3 x [8][1024][256]   12 MB
  ushort* WsBf = xT + 6291456;                  // Wq|Wk|Wv|Wo bf16    852 KB
  float*  attnF = (float*)(WsBf + 425984);      // [8][512][1024] fp32  16 MB

  prep_T<<<dim3(16, 12, 8), 256, 0, stream>>>(q_x, k_x, v_x, xT);
  prep_W<<<208, 256, 0, stream>>>(Wq, Wk, Wv, Wo, WsBf);

  conv_mfma<0><<<dim3(16, 2, 8), 256, 0, stream>>>(xT,           WsBf,          bq, wsQ, 0.125f);
  conv_mfma<0><<<dim3(16, 2, 8), 256, 0, stream>>>(xT + 2097152, WsBf + 131072, bk, wsK, 1.0f);
  conv_mfma<1><<<dim3(16, 2, 8), 256, 0, stream>>>(xT + 4194304, WsBf + 262144, bv, wsV, 1.0f);

  attn_mfma<<<dim3(16, 64), 256, 0, stream>>>(wsQ, wsK, wsV, krw, krh, attnF);

  outconv_mfma<<<dim3(16, 8), 256, 0, stream>>>(attnF, WsBf + 393216, bo, (float*)d_out);
}